// Round 2
// baseline (501.151 us; speedup 1.0000x reference)
//
#include <hip/hip_runtime.h>

typedef short  short8   __attribute__((ext_vector_type(8)));
typedef float  floatx4  __attribute__((ext_vector_type(4)));
typedef unsigned int uintx2 __attribute__((ext_vector_type(2)));

#define LOG2E_X2 2.8853900817779268f

__device__ __forceinline__ float tanh_fast(float a) {
    // tanh(a) = 1 - 2/(exp(2a)+1), exp(2a) = 2^(a*2*log2(e))
    float e = __builtin_amdgcn_exp2f(a * LOG2E_X2);
    return 1.0f - 2.0f * __builtin_amdgcn_rcpf(1.0f + e);
}

__device__ __forceinline__ unsigned short bf16rne(float f) {   // setup only
    unsigned u = __float_as_uint(f);
    u += 0x7FFFu + ((u >> 16) & 1u);
    return (unsigned short)(u >> 16);
}

// RNE-pack two f32 -> one dword of 2 bf16 (lo=a, hi=b): 5 VALU ops, no 16-bit inserts
__device__ __forceinline__ unsigned pk2(float a, float b) {
    unsigned ua = __float_as_uint(a), ub = __float_as_uint(b);
    ua += 0x7FFFu + ((ua >> 16) & 1u);
    ub += 0x7FFFu + ((ub >> 16) & 1u);
    return __builtin_amdgcn_perm(ub, ua, 0x07060302);   // {ua.hi16, ub.hi16}
}

// 512 blocks x 256 threads; block owns 64 ODE rows for all 64 MLP evals.
// hT = W1T(256x96) @ XT(96x64); outT = W2T(64x256) @ hT(256x64).
// Round 2: rt-half-split GEMM1 (acc1 32 regs peak, kill spills), perm-packed
// bf16 stores, persistent b1 frags, per-blk cd=(b2+bfr)*dlt fold.
__global__ __launch_bounds__(256, 2) void ode_mfma(
    const float* __restrict__ s_in,  const float* __restrict__ t_in,
    const float* __restrict__ phi_in,const float* __restrict__ bfr_in,
    const float* __restrict__ w1_in, const float* __restrict__ b1_in,
    const float* __restrict__ w2_in, const float* __restrict__ b2_in,
    float* __restrict__ out)
{
    const int tid  = threadIdx.x;
    const int wv   = tid >> 6;
    const int lane = tid & 63;
    const int l15  = lane & 15;
    const int q    = lane >> 4;
    const int wg   = blockIdx.x;
    const int sb   = wg >> 5;
    const int n0   = (wg & 31) << 6;
    const int rowg0 = sb * 2048 + n0;

    __shared__ __align__(16) unsigned short Atile[64][104];
    __shared__ __align__(16) unsigned short Hs[64][264];
    __shared__ float dls[8];

    const int d0 = wv * 16 + q * 4;    // lane's 4 consecutive d columns

    // ---- persistent register fragments ----
    short8 w1f[4][3];
#pragma unroll
    for (int ht = 0; ht < 4; ++ht)
#pragma unroll
        for (int kk = 0; kk < 3; ++kk) {
            short8 f;
#pragma unroll
            for (int j = 0; j < 8; ++j) {
                int k = kk * 32 + q * 8 + j;
                int hc = (wv * 4 + ht) * 16 + l15;
                f[j] = (short)bf16rne(w1_in[k * 256 + hc]);
            }
            w1f[ht][kk] = f;
        }
    short8 w2f[8];
#pragma unroll
    for (int kk = 0; kk < 8; ++kk) {
        short8 f;
#pragma unroll
        for (int j = 0; j < 8; ++j) {
            int k = kk * 32 + q * 8 + j;
            f[j] = (short)bf16rne(w2_in[k * 64 + wv * 16 + l15]);
        }
        w2f[kk] = f;
    }

    // b1 fragment per (ht): acc1 init values (C-layout: row=q*4+r within tile)
    floatx4 bb[4];
#pragma unroll
    for (int ht = 0; ht < 4; ++ht)
        bb[ht] = *(const floatx4*)(b1_in + (wv * 4 + ht) * 16 + q * 4);
    const floatx4 b2v = *(const floatx4*)(b2_in + d0);

    // RK4 state: lane owns (row = rt*16+l15, d = d0..d0+3)
    floatx4 xv[4], kacc[4];
#pragma unroll
    for (int rt = 0; rt < 4; ++rt) {
        int rg = rowg0 + rt * 16 + l15;
        xv[rt] = *(const floatx4*)(s_in + rg * 64 + d0);
        uintx2 px = { pk2(xv[rt][0], xv[rt][1]), pk2(xv[rt][2], xv[rt][3]) };
        *(uintx2*)&Atile[rt * 16 + l15][d0] = px;
    }
    // Phi -> Atile cols 64..95
#pragma unroll
    for (int it = 0; it < 2; ++it) {
        int c2 = tid * 2 + it;           // 0..511
        int row = c2 >> 3, cc = c2 & 7;
        floatx4 p = *(const floatx4*)(phi_in + (rowg0 + row) * 32 + cc * 4);
        uintx2 px = { pk2(p[0], p[1]), pk2(p[2], p[3]) };
        *(uintx2*)&Atile[row][64 + cc * 4] = px;
    }
    if (tid < 8) dls[tid] = t_in[sb * 9 + tid + 1] - t_in[sb * 9 + tid];

    __syncthreads();

    const floatx4 fzero = {0.f, 0.f, 0.f, 0.f};

#pragma unroll 1
    for (int blk = 0; blk < 8; ++blk) {
        const float dlt = dls[blk];
        // cd = (b2 + bfr)*dlt  (bfr re-read from global: L1-resident after blk 0)
        floatx4 cd[4];
#pragma unroll
        for (int rt = 0; rt < 4; ++rt) {
            int rg = rowg0 + rt * 16 + l15;
            cd[rt] = (b2v + *(const floatx4*)(bfr_in + rg * 64 + d0)) * dlt;
        }
#pragma unroll 1
        for (int stp = 0; stp < 2; ++stp) {
#pragma unroll 1
            for (int sub = 0; sub < 4; ++sub) {
                __syncthreads();   // A-tile writes visible

                // ---- GEMM1 in two rt-halves (acc1 peak = 32 VGPRs) ----
#pragma unroll
                for (int half = 0; half < 2; ++half) {
                    floatx4 acc1[4][2];
#pragma unroll
                    for (int ht = 0; ht < 4; ++ht)
#pragma unroll
                        for (int rr = 0; rr < 2; ++rr) acc1[ht][rr] = bb[ht];
#pragma unroll
                    for (int kk = 0; kk < 3; ++kk) {
                        short8 xb[2];
#pragma unroll
                        for (int rr = 0; rr < 2; ++rr)
                            xb[rr] = *(const short8*)&Atile[(half * 2 + rr) * 16 + l15][kk * 32 + q * 8];
#pragma unroll
                        for (int ht = 0; ht < 4; ++ht)
#pragma unroll
                            for (int rr = 0; rr < 2; ++rr)
                                acc1[ht][rr] = __builtin_amdgcn_mfma_f32_16x16x32_bf16(
                                    w1f[ht][kk], xb[rr], acc1[ht][rr], 0, 0, 0);
                    }
#pragma unroll
                    for (int ht = 0; ht < 4; ++ht)
#pragma unroll
                        for (int rr = 0; rr < 2; ++rr) {
                            uintx2 hp = { pk2(tanh_fast(acc1[ht][rr][0]), tanh_fast(acc1[ht][rr][1])),
                                          pk2(tanh_fast(acc1[ht][rr][2]), tanh_fast(acc1[ht][rr][3])) };
                            *(uintx2*)&Hs[(half * 2 + rr) * 16 + l15][(wv * 4 + ht) * 16 + q * 4] = hp;
                        }
                }
                __syncthreads();   // Hs visible; Atile reads done

                // ---- GEMM2 ----
                floatx4 acc2[4];
#pragma unroll
                for (int rt = 0; rt < 4; ++rt) acc2[rt] = fzero;
#pragma unroll
                for (int kk = 0; kk < 8; ++kk)
#pragma unroll
                    for (int rt = 0; rt < 4; ++rt) {
                        short8 hb = *(const short8*)&Hs[rt * 16 + l15][kk * 32 + q * 8];
                        acc2[rt] = __builtin_amdgcn_mfma_f32_16x16x32_bf16(
                            w2f[kk], hb, acc2[rt], 0, 0, 0);
                    }
                // ---- RK4 epilogue: kv = acc2*dlt + cd (single fma per elt) ----
#pragma unroll
                for (int rt = 0; rt < 4; ++rt) {
                    floatx4 kv = acc2[rt] * dlt + cd[rt];
                    floatx4 xe;
                    if (sub == 0)      { kacc[rt] = kv;            xe = xv[rt] + 0.25f * kv; }
                    else if (sub == 1) { kacc[rt] += 2.0f * kv;    xe = xv[rt] + 0.25f * kv; }
                    else if (sub == 2) { kacc[rt] += 2.0f * kv;    xe = xv[rt] + 0.5f  * kv; }
                    else               { xv[rt] += (kacc[rt] + kv) * (1.0f / 12.0f); xe = xv[rt]; }
                    uintx2 px = { pk2(xe[0], xe[1]), pk2(xe[2], xe[3]) };
                    *(uintx2*)&Atile[rt * 16 + l15][d0] = px;
                }
            }
        }
        const int ob = (sb * 8 + blk) * 2048;
#pragma unroll
        for (int rt = 0; rt < 4; ++rt)
            *(floatx4*)(out + (size_t)(ob + n0 + rt * 16 + l15) * 64 + d0) = xv[rt];
    }
}

extern "C" void kernel_launch(void* const* d_in, const int* in_sizes, int n_in,
                              void* d_out, int out_size, void* d_ws, size_t ws_size,
                              hipStream_t stream) {
    const float* s_in  = (const float*)d_in[0];
    const float* t_in  = (const float*)d_in[1];
    const float* phi   = (const float*)d_in[2];
    const float* bfr   = (const float*)d_in[3];
    const float* w1    = (const float*)d_in[4];
    const float* b1    = (const float*)d_in[5];
    const float* w2    = (const float*)d_in[6];
    const float* b2    = (const float*)d_in[7];
    ode_mfma<<<512, 256, 0, stream>>>(s_in, t_in, phi, bfr, w1, b1, w2, b2, (float*)d_out);
}

// Round 3
// 417.197 us; speedup vs baseline: 1.2012x; 1.2012x over previous
//
#include <hip/hip_runtime.h>

typedef short  short8   __attribute__((ext_vector_type(8)));
typedef float  floatx4  __attribute__((ext_vector_type(4)));
typedef unsigned int uintx2 __attribute__((ext_vector_type(2)));

#define LOG2E_X2 2.8853900817779268f

__device__ __forceinline__ float tanh_fast(float a) {
    // tanh(a) = 1 - 2/(exp(2a)+1)
    float e = __builtin_amdgcn_exp2f(a * LOG2E_X2);
    return 1.0f - 2.0f * __builtin_amdgcn_rcpf(1.0f + e);
}

__device__ __forceinline__ unsigned short bf16rne(float f) {   // setup only
    unsigned u = __float_as_uint(f);
    u += 0x7FFFu + ((u >> 16) & 1u);
    return (unsigned short)(u >> 16);
}

// RNE-pack two f32 -> dword of 2 bf16 (lo=a, hi=b).
#if __has_builtin(__builtin_amdgcn_cvt_pk_bf16_f32)
__device__ __forceinline__ unsigned pk2(float a, float b) {
    auto r = __builtin_amdgcn_cvt_pk_bf16_f32(a, b);   // D.lo=cvt(S0), D.hi=cvt(S1)
    unsigned u; __builtin_memcpy(&u, &r, 4);
    return u;
}
#else
__device__ __forceinline__ unsigned pk2(float a, float b) {
    unsigned ua = __float_as_uint(a), ub = __float_as_uint(b);
    ua += 0x7FFFu + ((ua >> 16) & 1u);
    ub += 0x7FFFu + ((ub >> 16) & 1u);
    return __builtin_amdgcn_perm(ub, ua, 0x07060302);
}
#endif

// 512 blocks x 256 threads; block owns 64 ODE rows for all 64 MLP evals.
// hT = W1T(256x96) @ XT(96x64); outT = W2T(64x256) @ hT(256x64).
// Round 3: R1 skeleton + C-operand seeding (b1 via LDS frags, fbv=b2+bfr
// persistent), kv = acc2*dlt, cvt_pk bf16 packing. No half-split, no per-blk
// global re-reads.
__global__ __launch_bounds__(256, 2) void ode_mfma(
    const float* __restrict__ s_in,  const float* __restrict__ t_in,
    const float* __restrict__ phi_in,const float* __restrict__ bfr_in,
    const float* __restrict__ w1_in, const float* __restrict__ b1_in,
    const float* __restrict__ w2_in, const float* __restrict__ b2_in,
    float* __restrict__ out)
{
    const int tid  = threadIdx.x;
    const int wv   = tid >> 6;
    const int lane = tid & 63;
    const int l15  = lane & 15;
    const int q    = lane >> 4;
    const int wg   = blockIdx.x;
    const int sb   = wg >> 5;
    const int n0   = (wg & 31) << 6;
    const int rowg0 = sb * 2048 + n0;

    __shared__ __align__(16) unsigned short Atile[64][104];
    __shared__ __align__(16) unsigned short Hs[64][264];
    __shared__ __align__(16) float b1s[256];
    __shared__ float dls[8];

    const int d0 = wv * 16 + q * 4;    // lane's 4 consecutive d columns

    // ---- persistent register fragments ----
    short8 w1f[4][3];
#pragma unroll
    for (int ht = 0; ht < 4; ++ht)
#pragma unroll
        for (int kk = 0; kk < 3; ++kk) {
            short8 f;
#pragma unroll
            for (int j = 0; j < 8; ++j) {
                int k = kk * 32 + q * 8 + j;
                int hc = (wv * 4 + ht) * 16 + l15;
                f[j] = (short)bf16rne(w1_in[k * 256 + hc]);
            }
            w1f[ht][kk] = f;
        }
    short8 w2f[8];
#pragma unroll
    for (int kk = 0; kk < 8; ++kk) {
        short8 f;
#pragma unroll
        for (int j = 0; j < 8; ++j) {
            int k = kk * 32 + q * 8 + j;
            f[j] = (short)bf16rne(w2_in[k * 64 + wv * 16 + l15]);
        }
        w2f[kk] = f;
    }

    // RK4 state: lane owns (row = rt*16+l15, d = d0..d0+3)
    floatx4 xv[4], kacc[4], fbv[4];
    {
        const floatx4 b2v = *(const floatx4*)(b2_in + d0);
#pragma unroll
        for (int rt = 0; rt < 4; ++rt) {
            int rg = rowg0 + rt * 16 + l15;
            xv[rt]  = *(const floatx4*)(s_in   + rg * 64 + d0);
            fbv[rt] = b2v + *(const floatx4*)(bfr_in + rg * 64 + d0);
            uintx2 px = { pk2(xv[rt][0], xv[rt][1]), pk2(xv[rt][2], xv[rt][3]) };
            *(uintx2*)&Atile[rt * 16 + l15][d0] = px;
        }
    }
    // Phi -> Atile cols 64..95
#pragma unroll
    for (int it = 0; it < 2; ++it) {
        int c2 = tid * 2 + it;           // 0..511
        int row = c2 >> 3, cc = c2 & 7;
        floatx4 p = *(const floatx4*)(phi_in + (rowg0 + row) * 32 + cc * 4);
        uintx2 px = { pk2(p[0], p[1]), pk2(p[2], p[3]) };
        *(uintx2*)&Atile[row][64 + cc * 4] = px;
    }
    if (tid < 64) *(floatx4*)&b1s[tid * 4] = *(const floatx4*)(b1_in + tid * 4);
    if (tid < 8)  dls[tid] = t_in[sb * 9 + tid + 1] - t_in[sb * 9 + tid];

    __syncthreads();

#pragma unroll 1
    for (int blk = 0; blk < 8; ++blk) {
        const float dlt = dls[blk];
#pragma unroll 1
        for (int stp = 0; stp < 2; ++stp) {
#pragma unroll 1
            for (int sub = 0; sub < 4; ++sub) {
                __syncthreads();   // A-tile writes visible

                // ---- GEMM1: acc1 seeded with b1 frags via C operand ----
                floatx4 acc1[4][4];
                {
                    floatx4 bbf[4];
#pragma unroll
                    for (int ht = 0; ht < 4; ++ht)
                        bbf[ht] = *(const floatx4*)&b1s[(wv * 4 + ht) * 16 + q * 4];
                    short8 xb[4];
#pragma unroll
                    for (int rt = 0; rt < 4; ++rt)
                        xb[rt] = *(const short8*)&Atile[rt * 16 + l15][q * 8];
#pragma unroll
                    for (int ht = 0; ht < 4; ++ht)
#pragma unroll
                        for (int rt = 0; rt < 4; ++rt)
                            acc1[ht][rt] = __builtin_amdgcn_mfma_f32_16x16x32_bf16(
                                w1f[ht][0], xb[rt], bbf[ht], 0, 0, 0);
                }
#pragma unroll
                for (int kk = 1; kk < 3; ++kk) {
                    short8 xb[4];
#pragma unroll
                    for (int rt = 0; rt < 4; ++rt)
                        xb[rt] = *(const short8*)&Atile[rt * 16 + l15][kk * 32 + q * 8];
#pragma unroll
                    for (int ht = 0; ht < 4; ++ht)
#pragma unroll
                        for (int rt = 0; rt < 4; ++rt)
                            acc1[ht][rt] = __builtin_amdgcn_mfma_f32_16x16x32_bf16(
                                w1f[ht][kk], xb[rt], acc1[ht][rt], 0, 0, 0);
                }
                // ---- tanh + pack to Hs ----
#pragma unroll
                for (int ht = 0; ht < 4; ++ht)
#pragma unroll
                    for (int rt = 0; rt < 4; ++rt) {
                        uintx2 hp = { pk2(tanh_fast(acc1[ht][rt][0]), tanh_fast(acc1[ht][rt][1])),
                                      pk2(tanh_fast(acc1[ht][rt][2]), tanh_fast(acc1[ht][rt][3])) };
                        *(uintx2*)&Hs[rt * 16 + l15][(wv * 4 + ht) * 16 + q * 4] = hp;
                    }
                __syncthreads();   // Hs visible; Atile reads done

                // ---- GEMM2: acc2 seeded with fbv = b2 + bfr via C operand ----
                floatx4 acc2[4];
#pragma unroll
                for (int rt = 0; rt < 4; ++rt) {
                    short8 hb = *(const short8*)&Hs[rt * 16 + l15][q * 8];
                    acc2[rt] = __builtin_amdgcn_mfma_f32_16x16x32_bf16(
                        w2f[0], hb, fbv[rt], 0, 0, 0);
                }
#pragma unroll
                for (int kk = 1; kk < 8; ++kk)
#pragma unroll
                    for (int rt = 0; rt < 4; ++rt) {
                        short8 hb = *(const short8*)&Hs[rt * 16 + l15][kk * 32 + q * 8];
                        acc2[rt] = __builtin_amdgcn_mfma_f32_16x16x32_bf16(
                            w2f[kk], hb, acc2[rt], 0, 0, 0);
                    }
                // ---- RK4 epilogue: kv = acc2 * dlt (bias/forcing already seeded) ----
#pragma unroll
                for (int rt = 0; rt < 4; ++rt) {
                    floatx4 kv = acc2[rt] * dlt;
                    floatx4 xe;
                    if (sub == 0)      { kacc[rt] = kv;            xe = xv[rt] + 0.25f * kv; }
                    else if (sub == 1) { kacc[rt] += 2.0f * kv;    xe = xv[rt] + 0.25f * kv; }
                    else if (sub == 2) { kacc[rt] += 2.0f * kv;    xe = xv[rt] + 0.5f  * kv; }
                    else               { xv[rt] += (kacc[rt] + kv) * (1.0f / 12.0f); xe = xv[rt]; }
                    uintx2 px = { pk2(xe[0], xe[1]), pk2(xe[2], xe[3]) };
                    *(uintx2*)&Atile[rt * 16 + l15][d0] = px;
                }
            }
        }
        const int ob = (sb * 8 + blk) * 2048;
#pragma unroll
        for (int rt = 0; rt < 4; ++rt)
            *(floatx4*)(out + (size_t)(ob + n0 + rt * 16 + l15) * 64 + d0) = xv[rt];
    }
}

extern "C" void kernel_launch(void* const* d_in, const int* in_sizes, int n_in,
                              void* d_out, int out_size, void* d_ws, size_t ws_size,
                              hipStream_t stream) {
    const float* s_in  = (const float*)d_in[0];
    const float* t_in  = (const float*)d_in[1];
    const float* phi   = (const float*)d_in[2];
    const float* bfr   = (const float*)d_in[3];
    const float* w1    = (const float*)d_in[4];
    const float* b1    = (const float*)d_in[5];
    const float* w2    = (const float*)d_in[6];
    const float* b2    = (const float*)d_in[7];
    ode_mfma<<<512, 256, 0, stream>>>(s_in, t_in, phi, bfr, w1, b1, w2, b2, (float*)d_out);
}